// Round 4
// baseline (244.432 us; speedup 1.0000x reference)
//
#include <hip/hip_runtime.h>

// All tensors float32. Output = concat(vec[3E], dist[E], switch[E], mask[E]).
//
// R2 post-mortem: 68us with ALL pipes idle (HBM 22%, VALU 8.5%, occ 55%).
// 3x fewer gather instrs (float4-packed nodes) was NEUTRAL -> bottleneck is
// per-CU L1 miss/fill throughput (~6.5 cyc per missed 64B line; ~25K random
// lines per CU). R3: nontemporal (nt, no-allocate) gather loads to skip the
// L1 fill path, 8 edges/thread for 16 outstanding gathers/wave, nt streaming
// stores. Value arithmetic is bit-exact-preserved (d<5 mask cliff): fp
// contract OFF, numpy op order, OCML sqrtf.

typedef float f32x4 __attribute__((ext_vector_type(4)));

__device__ __forceinline__ float4 ntload4(const float4* p) {
    f32x4 r = __builtin_nontemporal_load((const f32x4*)p);
    return make_float4(r.x, r.y, r.z, r.w);
}
__device__ __forceinline__ void ntstore4(float4* p, float a, float b, float c, float d) {
    f32x4 v = {a, b, c, d};
    __builtin_nontemporal_store(v, (f32x4*)p);
}

__device__ __forceinline__ void edge_math(
    float dx0, float dx1, float dx2,
    float sh0, float sh1, float sh2, const float c[9],
    float& v0, float& v1, float& v2, float& dist, float& sw, float& mk)
{
#pragma clang fp contract(off)
    float m0 = sh0 * c[0]; m0 = m0 + sh1 * c[3]; m0 = m0 + sh2 * c[6];
    float m1 = sh0 * c[1]; m1 = m1 + sh1 * c[4]; m1 = m1 + sh2 * c[7];
    float m2 = sh0 * c[2]; m2 = m2 + sh1 * c[5]; m2 = m2 + sh2 * c[8];
    v0 = dx0 + m0; v1 = dx1 + m1; v2 = dx2 + m2;
    float q = v0 * v0; q = q + v1 * v1; q = q + v2 * v2;
    dist = sqrtf(q);
    bool m = dist < 5.0f;
    float cv = cosf(dist * 0.62831853f);   // f32(pi/5)
    sw = m ? (0.5f * cv + 0.5f) : 0.0f;
    mk = m ? 1.0f : 0.0f;
}

// ---- prepass: coords[N,3] -> packed float4[N] in ws (16B-aligned: 1 line/node)
__global__ __launch_bounds__(256) void pack_coords_kernel(
    const float* __restrict__ coords, float4* __restrict__ packed, int n_nodes)
{
    int i = blockIdx.x * blockDim.x + threadIdx.x;
    if (i >= n_nodes) return;
    const float* p = coords + 3 * (size_t)i;
    packed[i] = make_float4(p[0], p[1], p[2], 0.0f);
}

// ---- main kernel: 8 edges/thread, nt gathers, nt streaming stores ----
__global__ __launch_bounds__(256) void GraphProcessor_64012192579962_kernel(
    const float4* __restrict__ packed,  // [N] xyz_
    const int*   __restrict__ esrc,     // [E]
    const int*   __restrict__ edst,     // [E]
    const float* __restrict__ shifts,   // [E,3]
    const float* __restrict__ cells,    // [9]
    float* __restrict__ out_vec,        // [E,3]
    float* __restrict__ out_dist,       // [E]
    float* __restrict__ out_sw,         // [E]
    float* __restrict__ out_mask,       // [E]
    int n_groups, int n_edges)
{
#pragma clang fp contract(off)
    int t = blockIdx.x * blockDim.x + threadIdx.x;
    if (t >= n_groups) return;

    float c[9];
#pragma unroll
    for (int i = 0; i < 9; ++i) c[i] = cells[i];   // uniform -> scalar loads

    const int e0 = 8 * t;

    if (e0 + 7 < n_edges) {
        int4 ssa = ((const int4*)esrc)[2 * t], ssb = ((const int4*)esrc)[2 * t + 1];
        int4 dda = ((const int4*)edst)[2 * t], ddb = ((const int4*)edst)[2 * t + 1];
        const float4* shp = (const float4*)(shifts + 24 * (size_t)t);
        float4 h0 = shp[0], h1 = shp[1], h2 = shp[2];
        float4 h3 = shp[3], h4 = shp[4], h5 = shp[5];

        // 16 independent nt gathers issued before any compute
        float4 s0 = ntload4(packed + ssa.x), s1 = ntload4(packed + ssa.y);
        float4 s2 = ntload4(packed + ssa.z), s3 = ntload4(packed + ssa.w);
        float4 s4 = ntload4(packed + ssb.x), s5 = ntload4(packed + ssb.y);
        float4 s6 = ntload4(packed + ssb.z), s7 = ntload4(packed + ssb.w);
        float4 d0 = ntload4(packed + dda.x), d1 = ntload4(packed + dda.y);
        float4 d2 = ntload4(packed + dda.z), d3 = ntload4(packed + dda.w);
        float4 d4 = ntload4(packed + ddb.x), d5 = ntload4(packed + ddb.y);
        float4 d6 = ntload4(packed + ddb.z), d7 = ntload4(packed + ddb.w);

        float v[24], di[8], sw[8], mk[8];
        edge_math(d0.x - s0.x, d0.y - s0.y, d0.z - s0.z, h0.x, h0.y, h0.z, c, v[0],  v[1],  v[2],  di[0], sw[0], mk[0]);
        edge_math(d1.x - s1.x, d1.y - s1.y, d1.z - s1.z, h0.w, h1.x, h1.y, c, v[3],  v[4],  v[5],  di[1], sw[1], mk[1]);
        edge_math(d2.x - s2.x, d2.y - s2.y, d2.z - s2.z, h1.z, h1.w, h2.x, c, v[6],  v[7],  v[8],  di[2], sw[2], mk[2]);
        edge_math(d3.x - s3.x, d3.y - s3.y, d3.z - s3.z, h2.y, h2.z, h2.w, c, v[9],  v[10], v[11], di[3], sw[3], mk[3]);
        edge_math(d4.x - s4.x, d4.y - s4.y, d4.z - s4.z, h3.x, h3.y, h3.z, c, v[12], v[13], v[14], di[4], sw[4], mk[4]);
        edge_math(d5.x - s5.x, d5.y - s5.y, d5.z - s5.z, h3.w, h4.x, h4.y, c, v[15], v[16], v[17], di[5], sw[5], mk[5]);
        edge_math(d6.x - s6.x, d6.y - s6.y, d6.z - s6.z, h4.z, h4.w, h5.x, c, v[18], v[19], v[20], di[6], sw[6], mk[6]);
        edge_math(d7.x - s7.x, d7.y - s7.y, d7.z - s7.z, h5.y, h5.z, h5.w, c, v[21], v[22], v[23], di[7], sw[7], mk[7]);

        float4* ov = (float4*)(out_vec + 24 * (size_t)t);
        ntstore4(ov + 0, v[0],  v[1],  v[2],  v[3]);
        ntstore4(ov + 1, v[4],  v[5],  v[6],  v[7]);
        ntstore4(ov + 2, v[8],  v[9],  v[10], v[11]);
        ntstore4(ov + 3, v[12], v[13], v[14], v[15]);
        ntstore4(ov + 4, v[16], v[17], v[18], v[19]);
        ntstore4(ov + 5, v[20], v[21], v[22], v[23]);
        float4* odp = (float4*)(out_dist + 8 * (size_t)t);
        ntstore4(odp + 0, di[0], di[1], di[2], di[3]);
        ntstore4(odp + 1, di[4], di[5], di[6], di[7]);
        float4* osp = (float4*)(out_sw + 8 * (size_t)t);
        ntstore4(osp + 0, sw[0], sw[1], sw[2], sw[3]);
        ntstore4(osp + 1, sw[4], sw[5], sw[6], sw[7]);
        float4* omp = (float4*)(out_mask + 8 * (size_t)t);
        ntstore4(omp + 0, mk[0], mk[1], mk[2], mk[3]);
        ntstore4(omp + 1, mk[4], mk[5], mk[6], mk[7]);
    } else {
        for (int e = e0; e < n_edges; ++e) {
            float4 s = packed[esrc[e]], d = packed[edst[e]];
            float v0, v1, v2, di, sw, mk;
            edge_math(d.x - s.x, d.y - s.y, d.z - s.z,
                      shifts[3 * (size_t)e], shifts[3 * (size_t)e + 1],
                      shifts[3 * (size_t)e + 2], c, v0, v1, v2, di, sw, mk);
            out_vec[3 * (size_t)e]     = v0;
            out_vec[3 * (size_t)e + 1] = v1;
            out_vec[3 * (size_t)e + 2] = v2;
            out_dist[e] = di;
            out_sw[e]   = sw;
            out_mask[e] = mk;
        }
    }
}

// ---- fallback (ws too small): 12B struct gathers straight from coords ----
struct F3 { float x, y, z; };

__global__ __launch_bounds__(256) void GraphProcessor_fallback_kernel(
    const float* __restrict__ coords,
    const int*   __restrict__ esrc,
    const int*   __restrict__ edst,
    const float* __restrict__ shifts,
    const float* __restrict__ cells,
    float* __restrict__ out_vec,
    float* __restrict__ out_dist,
    float* __restrict__ out_sw,
    float* __restrict__ out_mask,
    int n_quads, int n_edges)
{
#pragma clang fp contract(off)
    int t = blockIdx.x * blockDim.x + threadIdx.x;
    if (t >= n_quads) return;

    float c[9];
#pragma unroll
    for (int i = 0; i < 9; ++i) c[i] = cells[i];

    const F3* nodes = (const F3*)coords;
    const int e0 = 4 * t;

    if (e0 + 3 < n_edges) {
        int4 ss = ((const int4*)esrc)[t];
        int4 dd = ((const int4*)edst)[t];
        const float4* shp = (const float4*)(shifts + 12 * (size_t)t);
        float4 h0 = shp[0], h1 = shp[1], h2 = shp[2];

        F3 s0 = nodes[ss.x], s1 = nodes[ss.y], s2 = nodes[ss.z], s3 = nodes[ss.w];
        F3 d0 = nodes[dd.x], d1 = nodes[dd.y], d2 = nodes[dd.z], d3 = nodes[dd.w];

        float v[12], di[4], sw[4], mk[4];
        edge_math(d0.x - s0.x, d0.y - s0.y, d0.z - s0.z, h0.x, h0.y, h0.z, c, v[0], v[1],  v[2],  di[0], sw[0], mk[0]);
        edge_math(d1.x - s1.x, d1.y - s1.y, d1.z - s1.z, h0.w, h1.x, h1.y, c, v[3], v[4],  v[5],  di[1], sw[1], mk[1]);
        edge_math(d2.x - s2.x, d2.y - s2.y, d2.z - s2.z, h1.z, h1.w, h2.x, c, v[6], v[7],  v[8],  di[2], sw[2], mk[2]);
        edge_math(d3.x - s3.x, d3.y - s3.y, d3.z - s3.z, h2.y, h2.z, h2.w, c, v[9], v[10], v[11], di[3], sw[3], mk[3]);

        float4* ov = (float4*)(out_vec + 12 * (size_t)t);
        ov[0] = make_float4(v[0], v[1], v[2],  v[3]);
        ov[1] = make_float4(v[4], v[5], v[6],  v[7]);
        ov[2] = make_float4(v[8], v[9], v[10], v[11]);
        ((float4*)out_dist)[t] = make_float4(di[0], di[1], di[2], di[3]);
        ((float4*)out_sw)[t]   = make_float4(sw[0], sw[1], sw[2], sw[3]);
        ((float4*)out_mask)[t] = make_float4(mk[0], mk[1], mk[2], mk[3]);
    } else {
        for (int e = e0; e < n_edges; ++e) {
            F3 s = nodes[esrc[e]], d = nodes[edst[e]];
            float v0, v1, v2, di, sw, mk;
            edge_math(d.x - s.x, d.y - s.y, d.z - s.z,
                      shifts[3 * (size_t)e], shifts[3 * (size_t)e + 1],
                      shifts[3 * (size_t)e + 2], c, v0, v1, v2, di, sw, mk);
            out_vec[3 * (size_t)e]     = v0;
            out_vec[3 * (size_t)e + 1] = v1;
            out_vec[3 * (size_t)e + 2] = v2;
            out_dist[e] = di;
            out_sw[e]   = sw;
            out_mask[e] = mk;
        }
    }
}

extern "C" void kernel_launch(void* const* d_in, const int* in_sizes, int n_in,
                              void* d_out, int out_size, void* d_ws, size_t ws_size,
                              hipStream_t stream) {
    const float* coords = (const float*)d_in[0];
    const int*   esrc   = (const int*)d_in[1];
    const int*   edst   = (const int*)d_in[2];
    const float* shifts = (const float*)d_in[3];
    const float* cells  = (const float*)d_in[4];

    const int N = in_sizes[0] / 3;  // n_nodes
    const int E = in_sizes[1];      // n_edges

    float* out      = (float*)d_out;
    float* out_vec  = out;                     // [E,3]
    float* out_dist = out + 3 * (size_t)E;     // [E]
    float* out_sw   = out_dist + E;            // [E]
    float* out_mask = out_sw + E;              // [E]

    if (ws_size >= (size_t)N * sizeof(float4)) {
        float4* packed = (float4*)d_ws;
        pack_coords_kernel<<<(N + 255) / 256, 256, 0, stream>>>(coords, packed, N);
        const int n_groups = (E + 7) / 8;
        dim3 grid((n_groups + 255) / 256);
        GraphProcessor_64012192579962_kernel<<<grid, dim3(256), 0, stream>>>(
            packed, esrc, edst, shifts, cells,
            out_vec, out_dist, out_sw, out_mask, n_groups, E);
    } else {
        const int n_quads = (E + 3) / 4;
        dim3 grid((n_quads + 255) / 256);
        GraphProcessor_fallback_kernel<<<grid, dim3(256), 0, stream>>>(
            coords, esrc, edst, shifts, cells,
            out_vec, out_dist, out_sw, out_mask, n_quads, E);
    }
}

// Round 5
// 173.231 us; speedup vs baseline: 1.4110x; 1.4110x over previous
//
#include <hip/hip_runtime.h>

// All tensors float32. Output = concat(vec[3E], dist[E], switch[E], mask[E]).
//
// R3 post-mortem: nt loads killed L2 residency of the coords table (FETCH
// 39->175MB), dur 68->141us. Reverted. Standing model: per-CU divergent-miss
// throughput ~6.2 cyc/64B line (MSHR-limited); R2 = 25K lines/CU = 65us,
// measured 68. R4 probe: 2 edges/thread (2x wave count) to test whether the
// miss pipe is occupancy-limited or saturated. Value arithmetic bit-exact
// (d<5 mask cliff): fp contract OFF, numpy op order, OCML sqrtf.

__device__ __forceinline__ void edge_math(
    float dx0, float dx1, float dx2,
    float sh0, float sh1, float sh2, const float c[9],
    float& v0, float& v1, float& v2, float& dist, float& sw, float& mk)
{
#pragma clang fp contract(off)
    float m0 = sh0 * c[0]; m0 = m0 + sh1 * c[3]; m0 = m0 + sh2 * c[6];
    float m1 = sh0 * c[1]; m1 = m1 + sh1 * c[4]; m1 = m1 + sh2 * c[7];
    float m2 = sh0 * c[2]; m2 = m2 + sh1 * c[5]; m2 = m2 + sh2 * c[8];
    v0 = dx0 + m0; v1 = dx1 + m1; v2 = dx2 + m2;
    float q = v0 * v0; q = q + v1 * v1; q = q + v2 * v2;
    dist = sqrtf(q);
    bool m = dist < 5.0f;
    float cv = cosf(dist * 0.62831853f);   // f32(pi/5)
    sw = m ? (0.5f * cv + 0.5f) : 0.0f;
    mk = m ? 1.0f : 0.0f;
}

// ---- prepass: coords[N,3] -> packed float4[N] in ws (16B-aligned: 1 line/node)
__global__ __launch_bounds__(256) void pack_coords_kernel(
    const float* __restrict__ coords, float4* __restrict__ packed, int n_nodes)
{
    int i = blockIdx.x * blockDim.x + threadIdx.x;
    if (i >= n_nodes) return;
    const float* p = coords + 3 * (size_t)i;
    packed[i] = make_float4(p[0], p[1], p[2], 0.0f);
}

// ---- main kernel: 2 edges/thread, cached gathers, plain stores ----
__global__ __launch_bounds__(256) void GraphProcessor_64012192579962_kernel(
    const float4* __restrict__ packed,  // [N] xyz_
    const int*   __restrict__ esrc,     // [E]
    const int*   __restrict__ edst,     // [E]
    const float* __restrict__ shifts,   // [E,3]
    const float* __restrict__ cells,    // [9]
    float* __restrict__ out_vec,        // [E,3]
    float* __restrict__ out_dist,       // [E]
    float* __restrict__ out_sw,         // [E]
    float* __restrict__ out_mask,       // [E]
    int n_pairs, int n_edges)
{
#pragma clang fp contract(off)
    int t = blockIdx.x * blockDim.x + threadIdx.x;
    if (t >= n_pairs) return;

    float c[9];
#pragma unroll
    for (int i = 0; i < 9; ++i) c[i] = cells[i];   // uniform -> scalar loads

    const int e0 = 2 * t;

    if (e0 + 1 < n_edges) {
        int2 ss = ((const int2*)esrc)[t];
        int2 dd = ((const int2*)edst)[t];
        const float2* shp = (const float2*)(shifts + 6 * (size_t)t);  // 24B @ 8B align
        float2 g0 = shp[0], g1 = shp[1], g2 = shp[2];

        // 4 independent gathers issued before any compute
        float4 s0 = packed[ss.x], s1 = packed[ss.y];
        float4 d0 = packed[dd.x], d1 = packed[dd.y];

        float vA0, vA1, vA2, diA, swA, mkA;
        float vB0, vB1, vB2, diB, swB, mkB;
        edge_math(d0.x - s0.x, d0.y - s0.y, d0.z - s0.z, g0.x, g0.y, g1.x, c,
                  vA0, vA1, vA2, diA, swA, mkA);
        edge_math(d1.x - s1.x, d1.y - s1.y, d1.z - s1.z, g1.y, g2.x, g2.y, c,
                  vB0, vB1, vB2, diB, swB, mkB);

        float2* ov = (float2*)(out_vec + 6 * (size_t)t);  // 24B @ 8B align
        ov[0] = make_float2(vA0, vA1);
        ov[1] = make_float2(vA2, vB0);
        ov[2] = make_float2(vB1, vB2);
        ((float2*)out_dist)[t] = make_float2(diA, diB);
        ((float2*)out_sw)[t]   = make_float2(swA, swB);
        ((float2*)out_mask)[t] = make_float2(mkA, mkB);
    } else {
        for (int e = e0; e < n_edges; ++e) {
            float4 s = packed[esrc[e]], d = packed[edst[e]];
            float v0, v1, v2, di, sw, mk;
            edge_math(d.x - s.x, d.y - s.y, d.z - s.z,
                      shifts[3 * (size_t)e], shifts[3 * (size_t)e + 1],
                      shifts[3 * (size_t)e + 2], c, v0, v1, v2, di, sw, mk);
            out_vec[3 * (size_t)e]     = v0;
            out_vec[3 * (size_t)e + 1] = v1;
            out_vec[3 * (size_t)e + 2] = v2;
            out_dist[e] = di;
            out_sw[e]   = sw;
            out_mask[e] = mk;
        }
    }
}

// ---- fallback (ws too small): 12B struct gathers straight from coords ----
struct F3 { float x, y, z; };

__global__ __launch_bounds__(256) void GraphProcessor_fallback_kernel(
    const float* __restrict__ coords,
    const int*   __restrict__ esrc,
    const int*   __restrict__ edst,
    const float* __restrict__ shifts,
    const float* __restrict__ cells,
    float* __restrict__ out_vec,
    float* __restrict__ out_dist,
    float* __restrict__ out_sw,
    float* __restrict__ out_mask,
    int n_pairs, int n_edges)
{
#pragma clang fp contract(off)
    int t = blockIdx.x * blockDim.x + threadIdx.x;
    if (t >= n_pairs) return;

    float c[9];
#pragma unroll
    for (int i = 0; i < 9; ++i) c[i] = cells[i];

    const F3* nodes = (const F3*)coords;

    for (int e = 2 * t; e < n_edges && e < 2 * t + 2; ++e) {
        F3 s = nodes[esrc[e]], d = nodes[edst[e]];
        float v0, v1, v2, di, sw, mk;
        edge_math(d.x - s.x, d.y - s.y, d.z - s.z,
                  shifts[3 * (size_t)e], shifts[3 * (size_t)e + 1],
                  shifts[3 * (size_t)e + 2], c, v0, v1, v2, di, sw, mk);
        out_vec[3 * (size_t)e]     = v0;
        out_vec[3 * (size_t)e + 1] = v1;
        out_vec[3 * (size_t)e + 2] = v2;
        out_dist[e] = di;
        out_sw[e]   = sw;
        out_mask[e] = mk;
    }
}

extern "C" void kernel_launch(void* const* d_in, const int* in_sizes, int n_in,
                              void* d_out, int out_size, void* d_ws, size_t ws_size,
                              hipStream_t stream) {
    const float* coords = (const float*)d_in[0];
    const int*   esrc   = (const int*)d_in[1];
    const int*   edst   = (const int*)d_in[2];
    const float* shifts = (const float*)d_in[3];
    const float* cells  = (const float*)d_in[4];

    const int N = in_sizes[0] / 3;  // n_nodes
    const int E = in_sizes[1];      // n_edges

    float* out      = (float*)d_out;
    float* out_vec  = out;                     // [E,3]
    float* out_dist = out + 3 * (size_t)E;     // [E]
    float* out_sw   = out_dist + E;            // [E]
    float* out_mask = out_sw + E;              // [E]

    const int n_pairs = (E + 1) / 2;
    dim3 grid((n_pairs + 255) / 256);

    if (ws_size >= (size_t)N * sizeof(float4)) {
        float4* packed = (float4*)d_ws;
        pack_coords_kernel<<<(N + 255) / 256, 256, 0, stream>>>(coords, packed, N);
        GraphProcessor_64012192579962_kernel<<<grid, dim3(256), 0, stream>>>(
            packed, esrc, edst, shifts, cells,
            out_vec, out_dist, out_sw, out_mask, n_pairs, E);
    } else {
        GraphProcessor_fallback_kernel<<<grid, dim3(256), 0, stream>>>(
            coords, esrc, edst, shifts, cells,
            out_vec, out_dist, out_sw, out_mask, n_pairs, E);
    }
}